// Round 9
// baseline (234.289 us; speedup 1.0000x reference)
//
#include <hip/hip_runtime.h>
#include <hip/hip_bf16.h>
#include <math.h>

#define B_   2
#define N_   8000
#define C_   512
#define NH   8
#define HD   64
#define DD   20
#define DR   10
#define NSR  1000
#define C2   1024
#define EPSF 1e-6f
#define QSCALE (0.125f * 1.44269504088896f)  // hd^-0.5 * log2(e)

typedef __attribute__((ext_vector_type(8))) short short8;   // 8 bf16 = 4 VGPRs
typedef __attribute__((ext_vector_type(4))) float f32x4;

__device__ __forceinline__ ushort f2bf(float f) {   // RNE float->bf16
  uint u = __float_as_uint(f);
  u += 0x7FFF + ((u >> 16) & 1);
  return (ushort)(u >> 16);
}
__device__ __forceinline__ float bf2f(ushort u) {
  return __uint_as_float(((uint)u) << 16);
}
__device__ __forceinline__ uint pkbf(float a, float b) {  // pack 2xf32 -> 2xbf16 (RNE)
  __hip_bfloat162 h = __float22bfloat162_rn(make_float2(a, b));
  return *(uint*)&h;
}
__device__ __forceinline__ void gload_lds16(const ushort* gp, ushort* lp) {
  __builtin_amdgcn_global_load_lds(
      (const __attribute__((address_space(1))) uint*)gp,
      (__attribute__((address_space(3))) uint*)lp, 16, 0, 0);
}
// bijective XCD-contiguous block remap (m204). Default dispatch round-robins
// blocks across the 8 per-XCD L2s; this gives each XCD a CONTIGUOUS chunk of
// work ids so blocks sharing operand panels hit the same L2.
__device__ __forceinline__ int xcd_swz(int orig, int nwg) {
  const int q = nwg >> 3, r = nwg & 7;
  const int x = orig & 7, j = orig >> 3;
  return (x < r ? x * (q + 1) : r * (q + 1) + (x - r) * q) + j;
}

// ---------------- fused prep: weight transpose+convert, sr_w transpose, x->bf16 ----------------
// blocks [0,256): Wq ; [256,768): Wkv ; [768,1024): Wp ; 1024: sr_w ;
// [1025, 5025): convert x fp32 -> bf16 (8 elems/thread)
__global__ __launch_bounds__(256) void prep_all(
    const float* __restrict__ Wq, const float* __restrict__ Wkv,
    const float* __restrict__ Wp, const float* __restrict__ sr_w,
    const float* __restrict__ x,
    ushort* __restrict__ Wqt, ushort* __restrict__ Wkvt,
    ushort* __restrict__ Wpt, float* __restrict__ sr_wt,
    ushort* __restrict__ xb) {
  const int bid = blockIdx.x;
  if (bid >= 1025) {           // convert chunk
    int i = (bid - 1025) * 256 + threadIdx.x;   // < 1,024,000
    const float4* s = (const float4*)x + 2 * (size_t)i;
    float4 f0 = s[0], f1 = s[1];
    ushort u[8] = {f2bf(f0.x), f2bf(f0.y), f2bf(f0.z), f2bf(f0.w),
                   f2bf(f1.x), f2bf(f1.y), f2bf(f1.z), f2bf(f1.w)};
    *(uint4*)(xb + 8 * (size_t)i) = *(uint4*)u;
    return;
  }
  if (bid == 1024) {           // sr_w[c][27] -> sr_wt[27][c]
    for (int i = threadIdx.x; i < 27 * C_; i += 256) {
      int k = i / C_, c = i - k * C_;
      sr_wt[k * C_ + c] = sr_w[c * 27 + k];
    }
    return;
  }
  const float* W; ushort* Wt; int Nn, id;
  if (bid < 256)      { W = Wq;  Wt = Wqt;  Nn = C_;  id = bid; }
  else if (bid < 768) { W = Wkv; Wt = Wkvt; Nn = C2;  id = bid - 256; }
  else                { W = Wp;  Wt = Wpt;  Nn = C_;  id = bid - 768; }
  const int K = C_;
  const int k0 = (id & 15) * 32, n0 = (id >> 4) * 32;
  __shared__ float tile[32][33];
  const int tx = threadIdx.x & 31, ty = threadIdx.x >> 5;  // ty 0..7
  #pragma unroll
  for (int i = 0; i < 4; ++i)
    tile[ty + 8 * i][tx] = W[(size_t)(k0 + ty + 8 * i) * Nn + n0 + tx];
  __syncthreads();
  #pragma unroll
  for (int i = 0; i < 4; ++i)
    Wt[(size_t)(n0 + ty + 8 * i) * K + k0 + tx] = f2bf(tile[tx][ty + 8 * i]);
}

// ---------------- MFMA GEMM, prefetch-pipelined (1 barrier / k-iter) ----------------
template <bool BF16OUT>
__global__ __launch_bounds__(256) void gemm_mfma(
    const ushort* __restrict__ A, const ushort* __restrict__ Bt,
    const float* __restrict__ bias, void* __restrict__ Cout,
    int M, int Nn, int K, float oscale) {
  __shared__ __align__(16) ushort Asw[2][128 * 64];
  __shared__ __align__(16) ushort Bsw[2][128 * 64];
  const int tid = threadIdx.x;
  const int wave = tid >> 6, lane = tid & 63;
  const int l = lane & 15, q = lane >> 4;
  const int wm = (wave >> 1) * 64, wn = (wave & 1) * 64;
  // XCD-contiguous remap: blocks sharing an A-panel (same bm) land on one XCD
  const int nwg = gridDim.x * gridDim.y;
  const int wg = xcd_swz(blockIdx.y * gridDim.x + blockIdx.x, nwg);
  const int bm = (wg / gridDim.x) * 128, bn = (wg % gridDim.x) * 128;

  const int srow = lane >> 3;                   // 0..7
  const int schunk = (lane & 7) ^ srow;         // XOR-swizzled 8-elem chunk

  f32x4 acc[4][4];
  #pragma unroll
  for (int i = 0; i < 4; ++i)
    #pragma unroll
    for (int j = 0; j < 4; ++j) acc[i][j] = (f32x4){0.f, 0.f, 0.f, 0.f};

  const int iters = K >> 6;
  #pragma unroll
  for (int t = 0; t < 4; ++t) {
    const int a = wave * 4 + t;
    const int rowA = min(bm + 8 * a + srow, M - 1);
    gload_lds16(A + (size_t)rowA * K + schunk * 8, Asw[0] + a * 512);
    const int rowB = bn + 8 * a + srow;
    gload_lds16(Bt + (size_t)rowB * K + schunk * 8, Bsw[0] + a * 512);
  }

  for (int it = 0; it < iters; ++it) {
    __syncthreads();
    const int cur = it & 1;
    if (it + 1 < iters) {
      const int k0 = 64 * (it + 1);
      #pragma unroll
      for (int t = 0; t < 4; ++t) {
        const int a = wave * 4 + t;
        const int rowA = min(bm + 8 * a + srow, M - 1);
        gload_lds16(A + (size_t)rowA * K + k0 + schunk * 8, Asw[cur ^ 1] + a * 512);
        const int rowB = bn + 8 * a + srow;
        gload_lds16(Bt + (size_t)rowB * K + k0 + schunk * 8, Bsw[cur ^ 1] + a * 512);
      }
    }
    #pragma unroll
    for (int kc = 0; kc < 2; ++kc) {
      short8 af[4], bfr[4];
      const int cq = 4 * kc + q;
      #pragma unroll
      for (int i = 0; i < 4; ++i) {
        const int ra = wm + 16 * i + l;
        af[i] = *(const short8*)&Asw[cur][ra * 64 + ((cq ^ (ra & 7)) * 8)];
        const int rb = wn + 16 * i + l;
        bfr[i] = *(const short8*)&Bsw[cur][rb * 64 + ((cq ^ (rb & 7)) * 8)];
      }
      #pragma unroll
      for (int i = 0; i < 4; ++i)
        #pragma unroll
        for (int j = 0; j < 4; ++j)
          acc[i][j] = __builtin_amdgcn_mfma_f32_16x16x32_bf16(af[i], bfr[j], acc[i][j], 0, 0, 0);
    }
  }

  float bv[4];
  #pragma unroll
  for (int j = 0; j < 4; ++j) bv[j] = bias[bn + wn + 16 * j + l];
  #pragma unroll
  for (int i = 0; i < 4; ++i) {
    #pragma unroll
    for (int r = 0; r < 4; ++r) {
      const int row = bm + wm + 16 * i + 4 * q + r;
      if (row >= M) continue;
      #pragma unroll
      for (int j = 0; j < 4; ++j) {
        const float v = (acc[i][j][r] + bv[j]) * oscale;
        const int col = bn + wn + 16 * j + l;
        if (BF16OUT) ((ushort*)Cout)[(size_t)row * Nn + col] = f2bf(v);
        else         ((float*)Cout)[(size_t)row * Nn + col] = v;
      }
    }
  }
}

// ---------------- depthwise conv3d k3 s2 p1 + bias + LayerNorm -> bf16 ----------------
// one WAVE per output row, 8 channels/lane, vectorized, in-wave LN reduce.
__global__ __launch_bounds__(512) void conv_ln_kernel(
    const ushort* __restrict__ xb, const float* __restrict__ sr_wt,
    const float* __restrict__ sr_b, const float* __restrict__ sr_g,
    const float* __restrict__ sr_beta, ushort* __restrict__ xr_ln) {
  const int blk = xcd_swz(blockIdx.x, (B_ * NSR) / 8);
  const int wave = threadIdx.x >> 6, lane = threadIdx.x & 63;
  const int row = blk * 8 + wave;                  // 0..1999
  const int b = row / NSR, m = row % NSR;
  const int dr = m / 100, hr = (m / 10) % 10, wr = m % 10;
  const int c0 = lane * 8;

  float acc[8];
  #pragma unroll
  for (int e = 0; e < 8; ++e) acc[e] = 0.f;

  #pragma unroll
  for (int kd = 0; kd < 3; ++kd) {
    int din = 2 * dr + kd - 1;
    if (din < 0 || din >= DD) continue;
    #pragma unroll
    for (int kh = 0; kh < 3; ++kh) {
      int hin = 2 * hr + kh - 1;
      if (hin < 0 || hin >= DD) continue;
      #pragma unroll
      for (int kw = 0; kw < 3; ++kw) {
        int win = 2 * wr + kw - 1;
        if (win < 0 || win >= DD) continue;
        int nin = (din * DD + hin) * DD + win;
        short8 xv = *(const short8*)&xb[((size_t)b * N_ + nin) * C_ + c0];
        const float* wp = sr_wt + (kd * 9 + kh * 3 + kw) * C_ + c0;
        float4 w0 = *(const float4*)wp, w1 = *(const float4*)(wp + 4);
        acc[0] = fmaf(bf2f((ushort)xv[0]), w0.x, acc[0]);
        acc[1] = fmaf(bf2f((ushort)xv[1]), w0.y, acc[1]);
        acc[2] = fmaf(bf2f((ushort)xv[2]), w0.z, acc[2]);
        acc[3] = fmaf(bf2f((ushort)xv[3]), w0.w, acc[3]);
        acc[4] = fmaf(bf2f((ushort)xv[4]), w1.x, acc[4]);
        acc[5] = fmaf(bf2f((ushort)xv[5]), w1.y, acc[5]);
        acc[6] = fmaf(bf2f((ushort)xv[6]), w1.z, acc[6]);
        acc[7] = fmaf(bf2f((ushort)xv[7]), w1.w, acc[7]);
      }
    }
  }
  {
    float4 b0 = *(const float4*)&sr_b[c0], b1 = *(const float4*)&sr_b[c0 + 4];
    acc[0] += b0.x; acc[1] += b0.y; acc[2] += b0.z; acc[3] += b0.w;
    acc[4] += b1.x; acc[5] += b1.y; acc[6] += b1.z; acc[7] += b1.w;
  }
  float s1 = 0.f, s2 = 0.f;
  #pragma unroll
  for (int e = 0; e < 8; ++e) { s1 += acc[e]; s2 += acc[e] * acc[e]; }
  #pragma unroll
  for (int off = 32; off > 0; off >>= 1) {
    s1 += __shfl_xor(s1, off, 64);
    s2 += __shfl_xor(s2, off, 64);
  }
  const float mean = s1 * (1.f / C_);
  const float var = s2 * (1.f / C_) - mean * mean;
  const float r = rsqrtf(var + EPSF);
  float4 g0 = *(const float4*)&sr_g[c0], g1 = *(const float4*)&sr_g[c0 + 4];
  float4 e0 = *(const float4*)&sr_beta[c0], e1 = *(const float4*)&sr_beta[c0 + 4];
  const float gg[8] = {g0.x, g0.y, g0.z, g0.w, g1.x, g1.y, g1.z, g1.w};
  const float ee[8] = {e0.x, e0.y, e0.z, e0.w, e1.x, e1.y, e1.z, e1.w};
  ushort outv[8];
  #pragma unroll
  for (int e = 0; e < 8; ++e)
    outv[e] = f2bf((acc[e] - mean) * r * gg[e] + ee[e]);
  *(uint4*)&xr_ln[(size_t)row * C_ + c0] = *(uint4*)outv;
}

// ---------------- reformat KV bf16 into attention-ready swizzled slabs ----------------
__global__ __launch_bounds__(256) void reformat_kv(
    const ushort* __restrict__ KVh, ushort* __restrict__ Kg, ushort* __restrict__ Vg) {
  const int bh = blockIdx.x;            // b*8+h
  const int b = bh >> 3, h = bh & 7;
  const int tile = blockIdx.y;
  const int t0 = tile * 64;
  const size_t slab = ((size_t)bh * 16 + tile) * 4096;
  const int tid = threadIdx.x;
  #pragma unroll
  for (int i = 0; i < 2; ++i) {
    int w = tid + 256 * i;
    int key = w >> 3, ch = w & 7;
    int row = min(t0 + key, NSR - 1);
    uint4 v = *(const uint4*)&KVh[((size_t)b * NSR + row) * C2 + h * 64 + ch * 8];
    *(uint4*)&Kg[slab + key * 64 + ((ch ^ (key & 7)) * 8)] = v;
  }
  #pragma unroll
  for (int i = 0; i < 2; ++i) {
    int d = tid & 63, kc = (tid >> 6) + 4 * i;
    ushort u[8];
    #pragma unroll
    for (int e = 0; e < 8; ++e) {
      int row = min(t0 + kc * 8 + e, NSR - 1);
      u[e] = KVh[((size_t)b * NSR + row) * C2 + 512 + h * 64 + d];
    }
    *(uint4*)&Vg[slab + d * 64 + ((kc ^ (d & 7)) * 8)] = *(uint4*)u;
  }
}

// ---------------- MFMA flash attention v8: 4 waves, 64 queries/wave ----------------
// grid = (32, 16), block 256 = 4 waves, 64 queries/wave (4 subtiles of 16).
// Doubling queries/wave amortizes the per-tile K/V LDS fragment reads (the
// dominant LDS traffic) over 2x the queries; per-subtile immediate P
// round-trip (write Pl then read it in the same s iteration, per-wave private,
// no barrier) keeps one Pl buffer per wave -> LDS 35 KB, 2 blocks/CU.
__global__ __launch_bounds__(256, 2) void attn_mfma_kernel(
    const ushort* __restrict__ Qb, const ushort* __restrict__ Kg,
    const ushort* __restrict__ Vg, ushort* __restrict__ Ob) {
  __shared__ __align__(16) ushort Kb[64 * 64];
  __shared__ __align__(16) ushort Vt[64 * 64];
  __shared__ __align__(16) ushort Pl[4][16 * 72];

  const int tid = threadIdx.x;
  const int wg = xcd_swz(blockIdx.y * 32 + blockIdx.x, 512);
  const int bh = wg >> 5;                        // 16 K/V-slab groups of 32 blocks
  const int b = bh >> 3, h = bh & 7;
  const int wave = tid >> 6, lane = tid & 63;
  const int l = lane & 15, q = lane >> 4;
  const int qw = (wg & 31) * 256 + wave * 64;    // 256 q/block, 32 blocks = 8192

  short8 qf[4][2];
  #pragma unroll
  for (int s = 0; s < 4; ++s) {
    const int row = min(qw + s * 16 + l, N_ - 1);
    const ushort* qp = Qb + ((size_t)b * N_ + row) * C_ + h * HD + q * 8;
    qf[s][0] = *(const short8*)(qp);
    qf[s][1] = *(const short8*)(qp + 32);
  }

  f32x4 o[4][4];
  #pragma unroll
  for (int s = 0; s < 4; ++s)
    #pragma unroll
    for (int td = 0; td < 4; ++td) o[s][td] = (f32x4){0.f, 0.f, 0.f, 0.f};
  float lrun[4] = {0.f, 0.f, 0.f, 0.f};

  const ushort* Kslab = Kg + (size_t)bh * 16 * 4096;
  const ushort* Vslab = Vg + (size_t)bh * 16 * 4096;

  for (int tile = 0; tile < 16; ++tile) {
    __syncthreads();
    // 4 waves x 2 segs x 1KB each covers the 8KB K and 8KB V tiles
    #pragma unroll
    for (int i = 0; i < 2; ++i) {
      const int seg = wave * 2 + i;
      gload_lds16(Kslab + tile * 4096 + seg * 512 + lane * 8, Kb + seg * 512);
      gload_lds16(Vslab + tile * 4096 + seg * 512 + lane * 8, Vt + seg * 512);
    }
    __syncthreads();

    // ---- hoist K and V fragments once, reuse for all 4 subtiles ----
    short8 af[2][4], vf[2][4];
    #pragma unroll
    for (int kc = 0; kc < 2; ++kc) {
      const int cq = 4 * kc + q;
      #pragma unroll
      for (int t = 0; t < 4; ++t) {
        const int row = 16 * t + l;
        af[kc][t] = *(const short8*)&Kb[row * 64 + ((cq ^ (row & 7)) * 8)];
        vf[kc][t] = *(const short8*)&Vt[row * 64 + ((cq ^ (row & 7)) * 8)];
      }
    }
    // ---- per subtile: QK -> softmax -> P round-trip -> PV ----
    #pragma unroll
    for (int s = 0; s < 4; ++s) {
      f32x4 sv[4];
      #pragma unroll
      for (int t = 0; t < 4; ++t) sv[t] = (f32x4){0.f, 0.f, 0.f, 0.f};
      #pragma unroll
      for (int kc = 0; kc < 2; ++kc)
        #pragma unroll
        for (int t = 0; t < 4; ++t)
          sv[t] = __builtin_amdgcn_mfma_f32_16x16x32_bf16(af[kc][t], qf[s][kc], sv[t], 0, 0, 0);
      if (tile == 15) {
        #pragma unroll
        for (int t = 0; t < 4; ++t)
          #pragma unroll
          for (int r = 0; r < 4; ++r)
            if (960 + 16 * t + 4 * q + r >= NSR) sv[t][r] = -1e30f;
      }
      float ssum = 0.f;
      #pragma unroll
      for (int t = 0; t < 4; ++t)
        #pragma unroll
        for (int r = 0; r < 4; ++r) {
          float p = __builtin_amdgcn_exp2f(sv[t][r]);
          sv[t][r] = p;
          ssum += p;
        }
      ssum += __shfl_xor(ssum, 16, 64);
      ssum += __shfl_xor(ssum, 32, 64);
      lrun[s] += ssum;
      #pragma unroll
      for (int t = 0; t < 4; ++t) {
        uint w0 = pkbf(sv[t][0], sv[t][1]);
        uint w1 = pkbf(sv[t][2], sv[t][3]);
        *(uint2*)&Pl[wave][l * 72 + 16 * t + 4 * q] = make_uint2(w0, w1);
      }
      #pragma unroll
      for (int kc = 0; kc < 2; ++kc) {
        short8 pf = *(const short8*)&Pl[wave][l * 72 + 8 * q + 32 * kc];
        #pragma unroll
        for (int td = 0; td < 4; ++td)
          o[s][td] = __builtin_amdgcn_mfma_f32_16x16x32_bf16(pf, vf[kc][td], o[s][td], 0, 0, 0);
      }
    }
  }

  // ---- epilogue ----
  #pragma unroll
  for (int s = 0; s < 4; ++s) {
    float linv[4];
    #pragma unroll
    for (int r = 0; r < 4; ++r) {
      float lv = __shfl(lrun[s], 4 * q + r, 16);
      linv[r] = 1.0f / lv;
    }
    #pragma unroll
    for (int td = 0; td < 4; ++td)
      #pragma unroll
      for (int r = 0; r < 4; ++r) {
        const int query = qw + s * 16 + 4 * q + r;
        if (query < N_)
          Ob[((size_t)b * N_ + query) * C_ + h * HD + 16 * td + l] =
              f2bf(o[s][td][r] * linv[r]);
      }
  }
}

// ---------------- trilinear upsample identity + LN + add -> bf16 out-proj input ----------------
// one WAVE per output row, 8 channels/lane, short8 loads, in-wave LN reduce.
__global__ __launch_bounds__(512) void ident_ln_add_kernel(
    const ushort* __restrict__ KVh, const float* __restrict__ up_g,
    const float* __restrict__ up_beta, const ushort* __restrict__ Ob,
    ushort* __restrict__ Obb) {
  const int blk = xcd_swz(blockIdx.x, (B_ * N_) / 8);
  const int wave = threadIdx.x >> 6, lane = threadIdx.x & 63;
  const int row = blk * 8 + wave;                // 0..15999
  const int b = row / N_, n = row % N_;
  const int od = n / 400, oh = (n / 20) % 20, ow = n % 20;
  int i0[3], i1[3]; float w0[3], w1[3];
  int oo[3] = {od, oh, ow};
  #pragma unroll
  for (int a = 0; a < 3; ++a) {
    int t = oo[a] >> 1;
    if (oo[a] & 1) { i0[a] = t; i1[a] = (t + 1 < DR) ? t + 1 : DR - 1; w0[a] = 0.75f; w1[a] = 0.25f; }
    else           { i0[a] = (t - 1 >= 0) ? t - 1 : 0; i1[a] = t;      w0[a] = 0.25f; w1[a] = 0.75f; }
  }
  const int c0 = lane * 8;
  float val[8];
  #pragma unroll
  for (int e = 0; e < 8; ++e) val[e] = 0.f;
  #pragma unroll
  for (int jd = 0; jd < 2; ++jd) {
    int id = jd ? i1[0] : i0[0]; float wd = jd ? w1[0] : w0[0];
    #pragma unroll
    for (int jh = 0; jh < 2; ++jh) {
      int ih = jh ? i1[1] : i0[1]; float wh = jh ? w1[1] : w0[1];
      #pragma unroll
      for (int jw = 0; jw < 2; ++jw) {
        int iw = jw ? i1[2] : i0[2]; float ww = jw ? w1[2] : w0[2];
        int mm = (id * DR + ih) * DR + iw;
        float wt = wd * wh * ww;
        short8 v = *(const short8*)&KVh[((size_t)b * NSR + mm) * C2 + C_ + c0];
        #pragma unroll
        for (int e = 0; e < 8; ++e)
          val[e] = fmaf(wt, bf2f((ushort)v[e]), val[e]);
      }
    }
  }
  float s1 = 0.f, s2 = 0.f;
  #pragma unroll
  for (int e = 0; e < 8; ++e) { s1 += val[e]; s2 += val[e] * val[e]; }
  #pragma unroll
  for (int off = 32; off > 0; off >>= 1) {
    s1 += __shfl_xor(s1, off, 64);
    s2 += __shfl_xor(s2, off, 64);
  }
  const float mean = s1 * (1.f / C_);
  const float var = s2 * (1.f / C_) - mean * mean;
  const float r = rsqrtf(var + EPSF);
  float4 g0 = *(const float4*)&up_g[c0], g1 = *(const float4*)&up_g[c0 + 4];
  float4 e0 = *(const float4*)&up_beta[c0], e1 = *(const float4*)&up_beta[c0 + 4];
  const float gg[8] = {g0.x, g0.y, g0.z, g0.w, g1.x, g1.y, g1.z, g1.w};
  const float ee[8] = {e0.x, e0.y, e0.z, e0.w, e1.x, e1.y, e1.z, e1.w};
  short8 ov = *(const short8*)&Ob[(size_t)row * C_ + c0];
  ushort outv[8];
  #pragma unroll
  for (int e = 0; e < 8; ++e)
    outv[e] = f2bf(bf2f((ushort)ov[e]) + (val[e] - mean) * r * gg[e] + ee[e]);
  *(uint4*)&Obb[(size_t)row * C_ + c0] = *(uint4*)outv;
}

extern "C" void kernel_launch(void* const* d_in, const int* in_sizes, int n_in,
                              void* d_out, int out_size, void* d_ws, size_t ws_size,
                              hipStream_t stream) {
  (void)in_sizes; (void)n_in; (void)out_size; (void)ws_size;
  const float* x       = (const float*)d_in[0];
  const float* Wq      = (const float*)d_in[1];
  const float* bq      = (const float*)d_in[2];
  const float* Wkv     = (const float*)d_in[3];
  const float* bkv     = (const float*)d_in[4];
  const float* sr_w    = (const float*)d_in[5];
  const float* sr_b    = (const float*)d_in[6];
  const float* sr_g    = (const float*)d_in[7];
  const float* sr_beta = (const float*)d_in[8];
  const float* up_g    = (const float*)d_in[9];
  const float* up_beta = (const float*)d_in[10];
  const float* Wp      = (const float*)d_in[11];
  const float* bp      = (const float*)d_in[12];
  float* out = (float*)d_out;

  // workspace (ushort units, ~61.3 MB + 55 KB)
  ushort* xb   = (ushort*)d_ws;                 // 8,192,000 (aliased by Obb after q-proj/conv)
  ushort* Qb   = xb + 8192000;                  // 8,192,000
  ushort* Ob   = Qb + 8192000;                  // 8,192,000
  ushort* XRb  = Ob + 8192000;                  // 1,024,000
  ushort* KVh  = XRb + 1024000;                 // 2,048,000
  ushort* Kg   = KVh + 2048000;                 // 1,048,576
  ushort* Vg   = Kg + 1048576;                  // 1,048,576
  ushort* Wqt  = Vg + 1048576;                  //   262,144
  ushort* Wkvt = Wqt + 262144;                  //   524,288
  ushort* Wpt  = Wkvt + 524288;                 //   262,144
  float*  sr_wt = (float*)(Wpt + 262144);       //    13,824 f
  ushort* Obb  = xb;

  // 0) fused prep: weights + sr_w + x->bf16 (one kernel, one launch)
  prep_all<<<dim3(5025), 256, 0, stream>>>(Wq, Wkv, Wp, sr_w, x, Wqt, Wkvt, Wpt, sr_wt, xb);
  // 1) Qb = bf16((x @ Wq + bq) * qscale)
  gemm_mfma<true><<<dim3(4, 125), 256, 0, stream>>>(xb, Wqt, bq, Qb, B_ * N_, C_, C_, QSCALE);
  // 2) XRb = bf16(LN(conv3d_dw(x) + sr_b))   [wave-per-row, vectorized]
  conv_ln_kernel<<<dim3(B_ * NSR / 8), 512, 0, stream>>>(xb, sr_wt, sr_b, sr_g, sr_beta, XRb);
  // 3) KVh = bf16(XRb @ Wkv + bkv)
  gemm_mfma<true><<<dim3(8, 16), 256, 0, stream>>>(XRb, Wkvt, bkv, KVh, B_ * NSR, C2, C_, 1.0f);
  // 4) Kg/Vg = attention-ready swizzled slabs
  reformat_kv<<<dim3(16, 16), 256, 0, stream>>>(KVh, Kg, Vg);
  // 5) Ob = bf16(softmax(QK^T) V)   [v8: 4 waves, 64 q/wave]
  attn_mfma_kernel<<<dim3(32, 16), 256, 0, stream>>>(Qb, Kg, Vg, Ob);
  // 6) Obb = bf16(Ob + LN(upsample(v)))   [wave-per-row, vectorized]
  ident_ln_add_kernel<<<dim3(B_ * N_ / 8), 512, 0, stream>>>(KVh, up_g, up_beta, Ob, Obb);
  // 7) out = Obb @ Wp + bp (fp32)
  gemm_mfma<false><<<dim3(4, 125), 256, 0, stream>>>(Obb, Wpt, bp, out, B_ * N_, C_, C_, 1.0f);
}

// Round 10
// 234.198 us; speedup vs baseline: 1.0004x; 1.0004x over previous
//
#include <hip/hip_runtime.h>
#include <hip/hip_bf16.h>
#include <math.h>

#define B_   2
#define N_   8000
#define C_   512
#define NH   8
#define HD   64
#define DD   20
#define DR   10
#define NSR  1000
#define C2   1024
#define EPSF 1e-6f
#define QSCALE (0.125f * 1.44269504088896f)  // hd^-0.5 * log2(e)

typedef __attribute__((ext_vector_type(8))) short short8;   // 8 bf16 = 4 VGPRs
typedef __attribute__((ext_vector_type(4))) float f32x4;

__device__ __forceinline__ ushort f2bf(float f) {   // RNE float->bf16
  uint u = __float_as_uint(f);
  u += 0x7FFF + ((u >> 16) & 1);
  return (ushort)(u >> 16);
}
__device__ __forceinline__ float bf2f(ushort u) {
  return __uint_as_float(((uint)u) << 16);
}
__device__ __forceinline__ uint pkbf(float a, float b) {  // pack 2xf32 -> 2xbf16 (RNE)
  __hip_bfloat162 h = __float22bfloat162_rn(make_float2(a, b));
  return *(uint*)&h;
}
__device__ __forceinline__ void gload_lds16(const ushort* gp, ushort* lp) {
  __builtin_amdgcn_global_load_lds(
      (const __attribute__((address_space(1))) uint*)gp,
      (__attribute__((address_space(3))) uint*)lp, 16, 0, 0);
}
// bijective XCD-contiguous block remap (m204). Default dispatch round-robins
// blocks across the 8 per-XCD L2s; this gives each XCD a CONTIGUOUS chunk of
// work ids so blocks sharing operand panels hit the same L2.
__device__ __forceinline__ int xcd_swz(int orig, int nwg) {
  const int q = nwg >> 3, r = nwg & 7;
  const int x = orig & 7, j = orig >> 3;
  return (x < r ? x * (q + 1) : r * (q + 1) + (x - r) * q) + j;
}

// ---------------- fused prep: weight transpose+convert, sr_w transpose, x->bf16 ----------------
// blocks [0,256): Wq ; [256,768): Wkv ; [768,1024): Wp ; 1024: sr_w ;
// [1025, 5025): convert x fp32 -> bf16 (8 elems/thread)
__global__ __launch_bounds__(256) void prep_all(
    const float* __restrict__ Wq, const float* __restrict__ Wkv,
    const float* __restrict__ Wp, const float* __restrict__ sr_w,
    const float* __restrict__ x,
    ushort* __restrict__ Wqt, ushort* __restrict__ Wkvt,
    ushort* __restrict__ Wpt, float* __restrict__ sr_wt,
    ushort* __restrict__ xb) {
  const int bid = blockIdx.x;
  if (bid >= 1025) {           // convert chunk
    int i = (bid - 1025) * 256 + threadIdx.x;   // < 1,024,000
    const float4* s = (const float4*)x + 2 * (size_t)i;
    float4 f0 = s[0], f1 = s[1];
    ushort u[8] = {f2bf(f0.x), f2bf(f0.y), f2bf(f0.z), f2bf(f0.w),
                   f2bf(f1.x), f2bf(f1.y), f2bf(f1.z), f2bf(f1.w)};
    *(uint4*)(xb + 8 * (size_t)i) = *(uint4*)u;
    return;
  }
  if (bid == 1024) {           // sr_w[c][27] -> sr_wt[27][c]
    for (int i = threadIdx.x; i < 27 * C_; i += 256) {
      int k = i / C_, c = i - k * C_;
      sr_wt[k * C_ + c] = sr_w[c * 27 + k];
    }
    return;
  }
  const float* W; ushort* Wt; int Nn, id;
  if (bid < 256)      { W = Wq;  Wt = Wqt;  Nn = C_;  id = bid; }
  else if (bid < 768) { W = Wkv; Wt = Wkvt; Nn = C2;  id = bid - 256; }
  else                { W = Wp;  Wt = Wpt;  Nn = C_;  id = bid - 768; }
  const int K = C_;
  const int k0 = (id & 15) * 32, n0 = (id >> 4) * 32;
  __shared__ float tile[32][33];
  const int tx = threadIdx.x & 31, ty = threadIdx.x >> 5;  // ty 0..7
  #pragma unroll
  for (int i = 0; i < 4; ++i)
    tile[ty + 8 * i][tx] = W[(size_t)(k0 + ty + 8 * i) * Nn + n0 + tx];
  __syncthreads();
  #pragma unroll
  for (int i = 0; i < 4; ++i)
    Wt[(size_t)(n0 + ty + 8 * i) * K + k0 + tx] = f2bf(tile[tx][ty + 8 * i]);
}

// ---------------- MFMA GEMM, prefetch-pipelined (1 barrier / k-iter) ----------------
template <bool BF16OUT>
__global__ __launch_bounds__(256) void gemm_mfma(
    const ushort* __restrict__ A, const ushort* __restrict__ Bt,
    const float* __restrict__ bias, void* __restrict__ Cout,
    int M, int Nn, int K, float oscale) {
  __shared__ __align__(16) ushort Asw[2][128 * 64];
  __shared__ __align__(16) ushort Bsw[2][128 * 64];
  const int tid = threadIdx.x;
  const int wave = tid >> 6, lane = tid & 63;
  const int l = lane & 15, q = lane >> 4;
  const int wm = (wave >> 1) * 64, wn = (wave & 1) * 64;
  // XCD-contiguous remap: blocks sharing an A-panel (same bm) land on one XCD
  const int nwg = gridDim.x * gridDim.y;
  const int wg = xcd_swz(blockIdx.y * gridDim.x + blockIdx.x, nwg);
  const int bm = (wg / gridDim.x) * 128, bn = (wg % gridDim.x) * 128;

  const int srow = lane >> 3;                   // 0..7
  const int schunk = (lane & 7) ^ srow;         // XOR-swizzled 8-elem chunk

  f32x4 acc[4][4];
  #pragma unroll
  for (int i = 0; i < 4; ++i)
    #pragma unroll
    for (int j = 0; j < 4; ++j) acc[i][j] = (f32x4){0.f, 0.f, 0.f, 0.f};

  const int iters = K >> 6;
  #pragma unroll
  for (int t = 0; t < 4; ++t) {
    const int a = wave * 4 + t;
    const int rowA = min(bm + 8 * a + srow, M - 1);
    gload_lds16(A + (size_t)rowA * K + schunk * 8, Asw[0] + a * 512);
    const int rowB = bn + 8 * a + srow;
    gload_lds16(Bt + (size_t)rowB * K + schunk * 8, Bsw[0] + a * 512);
  }

  for (int it = 0; it < iters; ++it) {
    __syncthreads();
    const int cur = it & 1;
    if (it + 1 < iters) {
      const int k0 = 64 * (it + 1);
      #pragma unroll
      for (int t = 0; t < 4; ++t) {
        const int a = wave * 4 + t;
        const int rowA = min(bm + 8 * a + srow, M - 1);
        gload_lds16(A + (size_t)rowA * K + k0 + schunk * 8, Asw[cur ^ 1] + a * 512);
        const int rowB = bn + 8 * a + srow;
        gload_lds16(Bt + (size_t)rowB * K + k0 + schunk * 8, Bsw[cur ^ 1] + a * 512);
      }
    }
    #pragma unroll
    for (int kc = 0; kc < 2; ++kc) {
      short8 af[4], bfr[4];
      const int cq = 4 * kc + q;
      #pragma unroll
      for (int i = 0; i < 4; ++i) {
        const int ra = wm + 16 * i + l;
        af[i] = *(const short8*)&Asw[cur][ra * 64 + ((cq ^ (ra & 7)) * 8)];
        const int rb = wn + 16 * i + l;
        bfr[i] = *(const short8*)&Bsw[cur][rb * 64 + ((cq ^ (rb & 7)) * 8)];
      }
      #pragma unroll
      for (int i = 0; i < 4; ++i)
        #pragma unroll
        for (int j = 0; j < 4; ++j)
          acc[i][j] = __builtin_amdgcn_mfma_f32_16x16x32_bf16(af[i], bfr[j], acc[i][j], 0, 0, 0);
    }
  }

  float bv[4];
  #pragma unroll
  for (int j = 0; j < 4; ++j) bv[j] = bias[bn + wn + 16 * j + l];
  #pragma unroll
  for (int i = 0; i < 4; ++i) {
    #pragma unroll
    for (int r = 0; r < 4; ++r) {
      const int row = bm + wm + 16 * i + 4 * q + r;
      if (row >= M) continue;
      #pragma unroll
      for (int j = 0; j < 4; ++j) {
        const float v = (acc[i][j][r] + bv[j]) * oscale;
        const int col = bn + wn + 16 * j + l;
        if (BF16OUT) ((ushort*)Cout)[(size_t)row * Nn + col] = f2bf(v);
        else         ((float*)Cout)[(size_t)row * Nn + col] = v;
      }
    }
  }
}

// ---------------- depthwise conv3d k3 s2 p1 + bias + LayerNorm -> bf16 ----------------
// one WAVE per output row, 8 channels/lane, vectorized, in-wave LN reduce.
__global__ __launch_bounds__(512) void conv_ln_kernel(
    const ushort* __restrict__ xb, const float* __restrict__ sr_wt,
    const float* __restrict__ sr_b, const float* __restrict__ sr_g,
    const float* __restrict__ sr_beta, ushort* __restrict__ xr_ln) {
  const int blk = xcd_swz(blockIdx.x, (B_ * NSR) / 8);
  const int wave = threadIdx.x >> 6, lane = threadIdx.x & 63;
  const int row = blk * 8 + wave;                  // 0..1999
  const int b = row / NSR, m = row % NSR;
  const int dr = m / 100, hr = (m / 10) % 10, wr = m % 10;
  const int c0 = lane * 8;

  float acc[8];
  #pragma unroll
  for (int e = 0; e < 8; ++e) acc[e] = 0.f;

  #pragma unroll
  for (int kd = 0; kd < 3; ++kd) {
    int din = 2 * dr + kd - 1;
    if (din < 0 || din >= DD) continue;
    #pragma unroll
    for (int kh = 0; kh < 3; ++kh) {
      int hin = 2 * hr + kh - 1;
      if (hin < 0 || hin >= DD) continue;
      #pragma unroll
      for (int kw = 0; kw < 3; ++kw) {
        int win = 2 * wr + kw - 1;
        if (win < 0 || win >= DD) continue;
        int nin = (din * DD + hin) * DD + win;
        short8 xv = *(const short8*)&xb[((size_t)b * N_ + nin) * C_ + c0];
        const float* wp = sr_wt + (kd * 9 + kh * 3 + kw) * C_ + c0;
        float4 w0 = *(const float4*)wp, w1 = *(const float4*)(wp + 4);
        acc[0] = fmaf(bf2f((ushort)xv[0]), w0.x, acc[0]);
        acc[1] = fmaf(bf2f((ushort)xv[1]), w0.y, acc[1]);
        acc[2] = fmaf(bf2f((ushort)xv[2]), w0.z, acc[2]);
        acc[3] = fmaf(bf2f((ushort)xv[3]), w0.w, acc[3]);
        acc[4] = fmaf(bf2f((ushort)xv[4]), w1.x, acc[4]);
        acc[5] = fmaf(bf2f((ushort)xv[5]), w1.y, acc[5]);
        acc[6] = fmaf(bf2f((ushort)xv[6]), w1.z, acc[6]);
        acc[7] = fmaf(bf2f((ushort)xv[7]), w1.w, acc[7]);
      }
    }
  }
  {
    float4 b0 = *(const float4*)&sr_b[c0], b1 = *(const float4*)&sr_b[c0 + 4];
    acc[0] += b0.x; acc[1] += b0.y; acc[2] += b0.z; acc[3] += b0.w;
    acc[4] += b1.x; acc[5] += b1.y; acc[6] += b1.z; acc[7] += b1.w;
  }
  float s1 = 0.f, s2 = 0.f;
  #pragma unroll
  for (int e = 0; e < 8; ++e) { s1 += acc[e]; s2 += acc[e] * acc[e]; }
  #pragma unroll
  for (int off = 32; off > 0; off >>= 1) {
    s1 += __shfl_xor(s1, off, 64);
    s2 += __shfl_xor(s2, off, 64);
  }
  const float mean = s1 * (1.f / C_);
  const float var = s2 * (1.f / C_) - mean * mean;
  const float r = rsqrtf(var + EPSF);
  float4 g0 = *(const float4*)&sr_g[c0], g1 = *(const float4*)&sr_g[c0 + 4];
  float4 e0 = *(const float4*)&sr_beta[c0], e1 = *(const float4*)&sr_beta[c0 + 4];
  const float gg[8] = {g0.x, g0.y, g0.z, g0.w, g1.x, g1.y, g1.z, g1.w};
  const float ee[8] = {e0.x, e0.y, e0.z, e0.w, e1.x, e1.y, e1.z, e1.w};
  ushort outv[8];
  #pragma unroll
  for (int e = 0; e < 8; ++e)
    outv[e] = f2bf((acc[e] - mean) * r * gg[e] + ee[e]);
  *(uint4*)&xr_ln[(size_t)row * C_ + c0] = *(uint4*)outv;
}

// ---------------- reformat KV bf16 into attention-ready swizzled slabs ----------------
__global__ __launch_bounds__(256) void reformat_kv(
    const ushort* __restrict__ KVh, ushort* __restrict__ Kg, ushort* __restrict__ Vg) {
  const int bh = blockIdx.x;            // b*8+h
  const int b = bh >> 3, h = bh & 7;
  const int tile = blockIdx.y;
  const int t0 = tile * 64;
  const size_t slab = ((size_t)bh * 16 + tile) * 4096;
  const int tid = threadIdx.x;
  #pragma unroll
  for (int i = 0; i < 2; ++i) {
    int w = tid + 256 * i;
    int key = w >> 3, ch = w & 7;
    int row = min(t0 + key, NSR - 1);
    uint4 v = *(const uint4*)&KVh[((size_t)b * NSR + row) * C2 + h * 64 + ch * 8];
    *(uint4*)&Kg[slab + key * 64 + ((ch ^ (key & 7)) * 8)] = v;
  }
  #pragma unroll
  for (int i = 0; i < 2; ++i) {
    int d = tid & 63, kc = (tid >> 6) + 4 * i;
    ushort u[8];
    #pragma unroll
    for (int e = 0; e < 8; ++e) {
      int row = min(t0 + kc * 8 + e, NSR - 1);
      u[e] = KVh[((size_t)b * NSR + row) * C2 + 512 + h * 64 + d];
    }
    *(uint4*)&Vg[slab + d * 64 + ((kc ^ (d & 7)) * 8)] = *(uint4*)u;
  }
}

// ---------------- MFMA flash attention v9: round-3 per-wave geometry, 4-wave blocks ----------------
// grid = (64, 16), block 256 = 4 waves, 32 queries/wave (2 subtiles of 16) --
// identical per-wave work/registers to the proven round-3 config (51.3us),
// but partitioned as 4 blocks/CU x 4 waves instead of 2 x 8: each barrier
// couples only 4 waves, and the CU holds 4 independent blocks whose phases
// interleave (staging of one block overlaps compute of another). LDS 34 KB.
__global__ __launch_bounds__(256, 4) void attn_mfma_kernel(
    const ushort* __restrict__ Qb, const ushort* __restrict__ Kg,
    const ushort* __restrict__ Vg, ushort* __restrict__ Ob) {
  __shared__ __align__(16) ushort Kb[64 * 64];
  __shared__ __align__(16) ushort Vt[64 * 64];
  __shared__ __align__(16) ushort Pl[4][2][16 * 72];

  const int tid = threadIdx.x;
  const int wg = xcd_swz(blockIdx.y * 64 + blockIdx.x, 1024);
  const int bh = wg >> 6;                        // 16 K/V-slab groups of 64 blocks
  const int b = bh >> 3, h = bh & 7;
  const int wave = tid >> 6, lane = tid & 63;
  const int l = lane & 15, q = lane >> 4;
  const int qw = (wg & 63) * 128 + wave * 32;    // 64*128 = 8192 (tail clamped)

  short8 qf[2][2];
  #pragma unroll
  for (int s = 0; s < 2; ++s) {
    const int row = min(qw + s * 16 + l, N_ - 1);
    const ushort* qp = Qb + ((size_t)b * N_ + row) * C_ + h * HD + q * 8;
    qf[s][0] = *(const short8*)(qp);
    qf[s][1] = *(const short8*)(qp + 32);
  }

  f32x4 o[2][4];
  #pragma unroll
  for (int s = 0; s < 2; ++s)
    #pragma unroll
    for (int td = 0; td < 4; ++td) o[s][td] = (f32x4){0.f, 0.f, 0.f, 0.f};
  float lrun[2] = {0.f, 0.f};

  const ushort* Kslab = Kg + (size_t)bh * 16 * 4096;
  const ushort* Vslab = Vg + (size_t)bh * 16 * 4096;

  for (int tile = 0; tile < 16; ++tile) {
    __syncthreads();
    // 4 waves x 2 segs x 1KB each covers the 8KB K and 8KB V tiles
    #pragma unroll
    for (int i = 0; i < 2; ++i) {
      const int seg = wave * 2 + i;
      gload_lds16(Kslab + tile * 4096 + seg * 512 + lane * 8, Kb + seg * 512);
      gload_lds16(Vslab + tile * 4096 + seg * 512 + lane * 8, Vt + seg * 512);
    }
    __syncthreads();

    // ---- hoist K fragments (read once, use for both subtiles) ----
    short8 af[2][4];
    #pragma unroll
    for (int kc = 0; kc < 2; ++kc) {
      const int cq = 4 * kc + q;
      #pragma unroll
      for (int t = 0; t < 4; ++t) {
        const int row = 16 * t + l;
        af[kc][t] = *(const short8*)&Kb[row * 64 + ((cq ^ (row & 7)) * 8)];
      }
    }
    // ---- QK + softmax per subtile ----
    #pragma unroll
    for (int s = 0; s < 2; ++s) {
      f32x4 sv[4];
      #pragma unroll
      for (int t = 0; t < 4; ++t) sv[t] = (f32x4){0.f, 0.f, 0.f, 0.f};
      #pragma unroll
      for (int kc = 0; kc < 2; ++kc)
        #pragma unroll
        for (int t = 0; t < 4; ++t)
          sv[t] = __builtin_amdgcn_mfma_f32_16x16x32_bf16(af[kc][t], qf[s][kc], sv[t], 0, 0, 0);
      if (tile == 15) {
        #pragma unroll
        for (int t = 0; t < 4; ++t)
          #pragma unroll
          for (int r = 0; r < 4; ++r)
            if (960 + 16 * t + 4 * q + r >= NSR) sv[t][r] = -1e30f;
      }
      float ssum = 0.f;
      #pragma unroll
      for (int t = 0; t < 4; ++t)
        #pragma unroll
        for (int r = 0; r < 4; ++r) {
          float p = __builtin_amdgcn_exp2f(sv[t][r]);
          sv[t][r] = p;
          ssum += p;
        }
      ssum += __shfl_xor(ssum, 16, 64);
      ssum += __shfl_xor(ssum, 32, 64);
      lrun[s] += ssum;
      #pragma unroll
      for (int t = 0; t < 4; ++t) {
        uint w0 = pkbf(sv[t][0], sv[t][1]);
        uint w1 = pkbf(sv[t][2], sv[t][3]);
        *(uint2*)&Pl[wave][s][l * 72 + 16 * t + 4 * q] = make_uint2(w0, w1);
      }
    }
    // ---- hoist V fragments, then PV for both subtiles ----
    short8 vf[2][4];
    #pragma unroll
    for (int kc = 0; kc < 2; ++kc) {
      const int cq = 4 * kc + q;
      #pragma unroll
      for (int td = 0; td < 4; ++td) {
        const int row = 16 * td + l;
        vf[kc][td] = *(const short8*)&Vt[row * 64 + ((cq ^ (row & 7)) * 8)];
      }
    }
    #pragma unroll
    for (int s = 0; s < 2; ++s)
      #pragma unroll
      for (int kc = 0; kc < 2; ++kc) {
        short8 pf = *(const short8*)&Pl[wave][s][l * 72 + 8 * q + 32 * kc];
        #pragma unroll
        for (int td = 0; td < 4; ++td)
          o[s][td] = __builtin_amdgcn_mfma_f32_16x16x32_bf16(pf, vf[kc][td], o[s][td], 0, 0, 0);
      }
  }

  // ---- epilogue ----
  #pragma unroll
  for (int s = 0; s < 2; ++s) {
    float linv[4];
    #pragma unroll
    for (int r = 0; r < 4; ++r) {
      float lv = __shfl(lrun[s], 4 * q + r, 16);
      linv[r] = 1.0f / lv;
    }
    #pragma unroll
    for (int td = 0; td < 4; ++td)
      #pragma unroll
      for (int r = 0; r < 4; ++r) {
        const int query = qw + s * 16 + 4 * q + r;
        if (query < N_)
          Ob[((size_t)b * N_ + query) * C_ + h * HD + 16 * td + l] =
              f2bf(o[s][td][r] * linv[r]);
      }
  }
}

// ---------------- trilinear upsample identity + LN + add -> bf16 out-proj input ----------------
// one WAVE per output row, 8 channels/lane, short8 loads, in-wave LN reduce.
__global__ __launch_bounds__(512) void ident_ln_add_kernel(
    const ushort* __restrict__ KVh, const float* __restrict__ up_g,
    const float* __restrict__ up_beta, const ushort* __restrict__ Ob,
    ushort* __restrict__ Obb) {
  const int blk = xcd_swz(blockIdx.x, (B_ * N_) / 8);
  const int wave = threadIdx.x >> 6, lane = threadIdx.x & 63;
  const int row = blk * 8 + wave;                // 0..15999
  const int b = row / N_, n = row % N_;
  const int od = n / 400, oh = (n / 20) % 20, ow = n % 20;
  int i0[3], i1[3]; float w0[3], w1[3];
  int oo[3] = {od, oh, ow};
  #pragma unroll
  for (int a = 0; a < 3; ++a) {
    int t = oo[a] >> 1;
    if (oo[a] & 1) { i0[a] = t; i1[a] = (t + 1 < DR) ? t + 1 : DR - 1; w0[a] = 0.75f; w1[a] = 0.25f; }
    else           { i0[a] = (t - 1 >= 0) ? t - 1 : 0; i1[a] = t;      w0[a] = 0.25f; w1[a] = 0.75f; }
  }
  const int c0 = lane * 8;
  float val[8];
  #pragma unroll
  for (int e = 0; e < 8; ++e) val[e] = 0.f;
  #pragma unroll
  for (int jd = 0; jd < 2; ++jd) {
    int id = jd ? i1[0] : i0[0]; float wd = jd ? w1[0] : w0[0];
    #pragma unroll
    for (int jh = 0; jh < 2; ++jh) {
      int ih = jh ? i1[1] : i0[1]; float wh = jh ? w1[1] : w0[1];
      #pragma unroll
      for (int jw = 0; jw < 2; ++jw) {
        int iw = jw ? i1[2] : i0[2]; float ww = jw ? w1[2] : w0[2];
        int mm = (id * DR + ih) * DR + iw;
        float wt = wd * wh * ww;
        short8 v = *(const short8*)&KVh[((size_t)b * NSR + mm) * C2 + C_ + c0];
        #pragma unroll
        for (int e = 0; e < 8; ++e)
          val[e] = fmaf(wt, bf2f((ushort)v[e]), val[e]);
      }
    }
  }
  float s1 = 0.f, s2 = 0.f;
  #pragma unroll
  for (int e = 0; e < 8; ++e) { s1 += val[e]; s2 += val[e] * val[e]; }
  #pragma unroll
  for (int off = 32; off > 0; off >>= 1) {
    s1 += __shfl_xor(s1, off, 64);
    s2 += __shfl_xor(s2, off, 64);
  }
  const float mean = s1 * (1.f / C_);
  const float var = s2 * (1.f / C_) - mean * mean;
  const float r = rsqrtf(var + EPSF);
  float4 g0 = *(const float4*)&up_g[c0], g1 = *(const float4*)&up_g[c0 + 4];
  float4 e0 = *(const float4*)&up_beta[c0], e1 = *(const float4*)&up_beta[c0 + 4];
  const float gg[8] = {g0.x, g0.y, g0.z, g0.w, g1.x, g1.y, g1.z, g1.w};
  const float ee[8] = {e0.x, e0.y, e0.z, e0.w, e1.x, e1.y, e1.z, e1.w};
  short8 ov = *(const short8*)&Ob[(size_t)row * C_ + c0];
  ushort outv[8];
  #pragma unroll
  for (int e = 0; e < 8; ++e)
    outv[e] = f2bf(bf2f((ushort)ov[e]) + (val[e] - mean) * r * gg[e] + ee[e]);
  *(uint4*)&Obb[(size_t)row * C_ + c0] = *(uint4*)outv;
}

extern "C" void kernel_launch(void* const* d_in, const int* in_sizes, int n_in,
                              void* d_out, int out_size, void* d_ws, size_t ws_size,
                              hipStream_t stream) {
  (void)in_sizes; (void)n_in; (void)out_size; (void)ws_size;
  const float* x       = (const float*)d_in[0];
  const float* Wq      = (const float*)d_in[1];
  const float* bq      = (const float*)d_in[2];
  const float* Wkv     = (const float*)d_in[3];
  const float* bkv     = (const float*)d_in[4];
  const float* sr_w    = (const float*)d_in[5];
  const float* sr_b    = (const float*)d_in[6];
  const float* sr_g    = (const float*)d_in[7];
  const float* sr_beta = (const float*)d_in[8];
  const float* up_g    = (const float*)d_in[9];
  const float* up_beta = (const float*)d_in[10];
  const float* Wp      = (const float*)d_in[11];
  const float* bp      = (const float*)d_in[12];
  float* out = (float*)d_out;

  // workspace (ushort units, ~61.3 MB + 55 KB)
  ushort* xb   = (ushort*)d_ws;                 // 8,192,000 (aliased by Obb after q-proj/conv)
  ushort* Qb   = xb + 8192000;                  // 8,192,000
  ushort* Ob   = Qb + 8192000;                  // 8,192,000
  ushort* XRb  = Ob + 8192000;                  // 1,024,000
  ushort* KVh  = XRb + 1024000;                 // 2,048,000
  ushort* Kg   = KVh + 2048000;                 // 1,048,576
  ushort* Vg   = Kg + 1048576;                  // 1,048,576
  ushort* Wqt  = Vg + 1048576;                  //   262,144
  ushort* Wkvt = Wqt + 262144;                  //   524,288
  ushort* Wpt  = Wkvt + 524288;                 //   262,144
  float*  sr_wt = (float*)(Wpt + 262144);       //    13,824 f
  ushort* Obb  = xb;

  // 0) fused prep: weights + sr_w + x->bf16 (one kernel, one launch)
  prep_all<<<dim3(5025), 256, 0, stream>>>(Wq, Wkv, Wp, sr_w, x, Wqt, Wkvt, Wpt, sr_wt, xb);
  // 1) Qb = bf16((x @ Wq + bq) * qscale)
  gemm_mfma<true><<<dim3(4, 125), 256, 0, stream>>>(xb, Wqt, bq, Qb, B_ * N_, C_, C_, QSCALE);
  // 2) XRb = bf16(LN(conv3d_dw(x) + sr_b))   [wave-per-row, vectorized]
  conv_ln_kernel<<<dim3(B_ * NSR / 8), 512, 0, stream>>>(xb, sr_wt, sr_b, sr_g, sr_beta, XRb);
  // 3) KVh = bf16(XRb @ Wkv + bkv)
  gemm_mfma<true><<<dim3(8, 16), 256, 0, stream>>>(XRb, Wkvt, bkv, KVh, B_ * NSR, C2, C_, 1.0f);
  // 4) Kg/Vg = attention-ready swizzled slabs
  reformat_kv<<<dim3(16, 16), 256, 0, stream>>>(KVh, Kg, Vg);
  // 5) Ob = bf16(softmax(QK^T) V)   [v9: 4-wave blocks, 32 q/wave, 4 blocks/CU]
  attn_mfma_kernel<<<dim3(64, 16), 256, 0, stream>>>(Qb, Kg, Vg, Ob);
  // 6) Obb = bf16(Ob + LN(upsample(v)))   [wave-per-row, vectorized]
  ident_ln_add_kernel<<<dim3(B_ * N_ / 8), 512, 0, stream>>>(KVh, up_g, up_beta, Ob, Obb);
  // 7) out = Obb @ Wp + bp (fp32)
  gemm_mfma<false><<<dim3(4, 125), 256, 0, stream>>>(Obb, Wpt, bp, out, B_ * N_, C_, C_, 1.0f);
}

// Round 11
// 227.547 us; speedup vs baseline: 1.0296x; 1.0292x over previous
//
#include <hip/hip_runtime.h>
#include <hip/hip_bf16.h>
#include <math.h>

#define B_   2
#define N_   8000
#define C_   512
#define NH   8
#define HD   64
#define DD   20
#define DR   10
#define NSR  1000
#define C2   1024
#define EPSF 1e-6f
#define QSCALE (0.125f * 1.44269504088896f)  // hd^-0.5 * log2(e)

typedef __attribute__((ext_vector_type(8))) short short8;   // 8 bf16 = 4 VGPRs
typedef __attribute__((ext_vector_type(4))) float f32x4;

__device__ __forceinline__ ushort f2bf(float f) {   // RNE float->bf16
  uint u = __float_as_uint(f);
  u += 0x7FFF + ((u >> 16) & 1);
  return (ushort)(u >> 16);
}
__device__ __forceinline__ float bf2f(ushort u) {
  return __uint_as_float(((uint)u) << 16);
}
__device__ __forceinline__ uint pkbf(float a, float b) {  // pack 2xf32 -> 2xbf16 (RNE)
  __hip_bfloat162 h = __float22bfloat162_rn(make_float2(a, b));
  return *(uint*)&h;
}
__device__ __forceinline__ void gload_lds16(const ushort* gp, ushort* lp) {
  __builtin_amdgcn_global_load_lds(
      (const __attribute__((address_space(1))) uint*)gp,
      (__attribute__((address_space(3))) uint*)lp, 16, 0, 0);
}
// bijective XCD-contiguous block remap (m204). Default dispatch round-robins
// blocks across the 8 per-XCD L2s; this gives each XCD a CONTIGUOUS chunk of
// work ids so blocks sharing operand panels hit the same L2.
__device__ __forceinline__ int xcd_swz(int orig, int nwg) {
  const int q = nwg >> 3, r = nwg & 7;
  const int x = orig & 7, j = orig >> 3;
  return (x < r ? x * (q + 1) : r * (q + 1) + (x - r) * q) + j;
}

// ---------------- fused prep: weight transpose+convert, sr_w transpose, x->bf16 ----------------
// blocks [0,256): Wq ; [256,768): Wkv ; [768,1024): Wp ; 1024: sr_w ;
// [1025, 5025): convert x fp32 -> bf16 (8 elems/thread)
__global__ __launch_bounds__(256) void prep_all(
    const float* __restrict__ Wq, const float* __restrict__ Wkv,
    const float* __restrict__ Wp, const float* __restrict__ sr_w,
    const float* __restrict__ x,
    ushort* __restrict__ Wqt, ushort* __restrict__ Wkvt,
    ushort* __restrict__ Wpt, float* __restrict__ sr_wt,
    ushort* __restrict__ xb) {
  const int bid = blockIdx.x;
  if (bid >= 1025) {           // convert chunk
    int i = (bid - 1025) * 256 + threadIdx.x;   // < 1,024,000
    const float4* s = (const float4*)x + 2 * (size_t)i;
    float4 f0 = s[0], f1 = s[1];
    ushort u[8] = {f2bf(f0.x), f2bf(f0.y), f2bf(f0.z), f2bf(f0.w),
                   f2bf(f1.x), f2bf(f1.y), f2bf(f1.z), f2bf(f1.w)};
    *(uint4*)(xb + 8 * (size_t)i) = *(uint4*)u;
    return;
  }
  if (bid == 1024) {           // sr_w[c][27] -> sr_wt[27][c]
    for (int i = threadIdx.x; i < 27 * C_; i += 256) {
      int k = i / C_, c = i - k * C_;
      sr_wt[k * C_ + c] = sr_w[c * 27 + k];
    }
    return;
  }
  const float* W; ushort* Wt; int Nn, id;
  if (bid < 256)      { W = Wq;  Wt = Wqt;  Nn = C_;  id = bid; }
  else if (bid < 768) { W = Wkv; Wt = Wkvt; Nn = C2;  id = bid - 256; }
  else                { W = Wp;  Wt = Wpt;  Nn = C_;  id = bid - 768; }
  const int K = C_;
  const int k0 = (id & 15) * 32, n0 = (id >> 4) * 32;
  __shared__ float tile[32][33];
  const int tx = threadIdx.x & 31, ty = threadIdx.x >> 5;  // ty 0..7
  #pragma unroll
  for (int i = 0; i < 4; ++i)
    tile[ty + 8 * i][tx] = W[(size_t)(k0 + ty + 8 * i) * Nn + n0 + tx];
  __syncthreads();
  #pragma unroll
  for (int i = 0; i < 4; ++i)
    Wt[(size_t)(n0 + ty + 8 * i) * K + k0 + tx] = f2bf(tile[tx][ty + 8 * i]);
}

// ---------------- shared MFMA GEMM core (prefetch-pipelined, 1 barrier / k-iter) ----------------
// bf16 output. Asw/Bsw are 2x(128*64) double buffers in LDS.
__device__ __forceinline__ void gemm_core(
    const ushort* __restrict__ A, const ushort* __restrict__ Bt,
    const float* __restrict__ bias, ushort* __restrict__ Cout,
    int M, int Nn, int K, float oscale, int wg, int gx,
    ushort* __restrict__ AswB, ushort* __restrict__ BswB) {
  const int tid = threadIdx.x;
  const int wave = tid >> 6, lane = tid & 63;
  const int l = lane & 15, q = lane >> 4;
  const int wm = (wave >> 1) * 64, wn = (wave & 1) * 64;
  const int bm = (wg / gx) * 128, bn = (wg % gx) * 128;

  const int srow = lane >> 3;                   // 0..7
  const int schunk = (lane & 7) ^ srow;         // XOR-swizzled 8-elem chunk

  f32x4 acc[4][4];
  #pragma unroll
  for (int i = 0; i < 4; ++i)
    #pragma unroll
    for (int j = 0; j < 4; ++j) acc[i][j] = (f32x4){0.f, 0.f, 0.f, 0.f};

  const int iters = K >> 6;
  #pragma unroll
  for (int t = 0; t < 4; ++t) {
    const int a = wave * 4 + t;
    const int rowA = min(bm + 8 * a + srow, M - 1);
    gload_lds16(A + (size_t)rowA * K + schunk * 8, AswB + a * 512);
    const int rowB = bn + 8 * a + srow;
    gload_lds16(Bt + (size_t)rowB * K + schunk * 8, BswB + a * 512);
  }

  for (int it = 0; it < iters; ++it) {
    __syncthreads();
    const int cur = it & 1;
    if (it + 1 < iters) {
      const int k0 = 64 * (it + 1);
      #pragma unroll
      for (int t = 0; t < 4; ++t) {
        const int a = wave * 4 + t;
        const int rowA = min(bm + 8 * a + srow, M - 1);
        gload_lds16(A + (size_t)rowA * K + k0 + schunk * 8,
                    AswB + (cur ^ 1) * 8192 + a * 512);
        const int rowB = bn + 8 * a + srow;
        gload_lds16(Bt + (size_t)rowB * K + k0 + schunk * 8,
                    BswB + (cur ^ 1) * 8192 + a * 512);
      }
    }
    #pragma unroll
    for (int kc = 0; kc < 2; ++kc) {
      short8 af[4], bfr[4];
      const int cq = 4 * kc + q;
      #pragma unroll
      for (int i = 0; i < 4; ++i) {
        const int ra = wm + 16 * i + l;
        af[i] = *(const short8*)&AswB[cur * 8192 + ra * 64 + ((cq ^ (ra & 7)) * 8)];
        const int rb = wn + 16 * i + l;
        bfr[i] = *(const short8*)&BswB[cur * 8192 + rb * 64 + ((cq ^ (rb & 7)) * 8)];
      }
      #pragma unroll
      for (int i = 0; i < 4; ++i)
        #pragma unroll
        for (int j = 0; j < 4; ++j)
          acc[i][j] = __builtin_amdgcn_mfma_f32_16x16x32_bf16(af[i], bfr[j], acc[i][j], 0, 0, 0);
    }
  }

  float bv[4];
  #pragma unroll
  for (int j = 0; j < 4; ++j) bv[j] = bias[bn + wn + 16 * j + l];
  #pragma unroll
  for (int i = 0; i < 4; ++i) {
    #pragma unroll
    for (int r = 0; r < 4; ++r) {
      const int row = bm + wm + 16 * i + 4 * q + r;
      if (row >= M) continue;
      #pragma unroll
      for (int j = 0; j < 4; ++j) {
        const float v = (acc[i][j][r] + bv[j]) * oscale;
        const int col = bn + wn + 16 * j + l;
        Cout[(size_t)row * Nn + col] = f2bf(v);
      }
    }
  }
}

// ---------------- fused dual GEMM: Q-proj (500 blocks) + KV-proj (128 blocks) ----------------
// The two GEMMs are independent (Q needs xb; KV needs XRb from conv_ln which
// runs first). Fusing them fills the machine: KV's 128 blocks ride along with
// Q's 500 instead of occupying a serial dispatch at 50% machine idle.
__global__ __launch_bounds__(256) void gemm_dual(
    const ushort* __restrict__ xb, const ushort* __restrict__ Wqt,
    const float* __restrict__ bq, ushort* __restrict__ Qb,
    const ushort* __restrict__ XRb, const ushort* __restrict__ Wkvt,
    const float* __restrict__ bkv, ushort* __restrict__ KVh) {
  __shared__ __align__(16) ushort Asw[2][128 * 64];
  __shared__ __align__(16) ushort Bsw[2][128 * 64];
  const int bid = blockIdx.x;
  if (bid < 500) {
    gemm_core(xb, Wqt, bq, Qb, B_ * N_, C_, C_, QSCALE,
              xcd_swz(bid, 500), 4, &Asw[0][0], &Bsw[0][0]);
  } else {
    gemm_core(XRb, Wkvt, bkv, KVh, B_ * NSR, C2, C_, 1.0f,
              xcd_swz(bid - 500, 128), 8, &Asw[0][0], &Bsw[0][0]);
  }
}

// ---------------- standalone GEMM (fp32 out) for the out-projection ----------------
__global__ __launch_bounds__(256) void gemm_mfma_f32(
    const ushort* __restrict__ A, const ushort* __restrict__ Bt,
    const float* __restrict__ bias, float* __restrict__ Cout,
    int M, int Nn, int K) {
  __shared__ __align__(16) ushort Asw[2][128 * 64];
  __shared__ __align__(16) ushort Bsw[2][128 * 64];
  const int tid = threadIdx.x;
  const int wave = tid >> 6, lane = tid & 63;
  const int l = lane & 15, q = lane >> 4;
  const int wm = (wave >> 1) * 64, wn = (wave & 1) * 64;
  const int nwg = gridDim.x * gridDim.y;
  const int wg = xcd_swz(blockIdx.y * gridDim.x + blockIdx.x, nwg);
  const int bm = (wg / gridDim.x) * 128, bn = (wg % gridDim.x) * 128;

  const int srow = lane >> 3;
  const int schunk = (lane & 7) ^ srow;

  f32x4 acc[4][4];
  #pragma unroll
  for (int i = 0; i < 4; ++i)
    #pragma unroll
    for (int j = 0; j < 4; ++j) acc[i][j] = (f32x4){0.f, 0.f, 0.f, 0.f};

  const int iters = K >> 6;
  #pragma unroll
  for (int t = 0; t < 4; ++t) {
    const int a = wave * 4 + t;
    const int rowA = min(bm + 8 * a + srow, M - 1);
    gload_lds16(A + (size_t)rowA * K + schunk * 8, Asw[0] + a * 512);
    const int rowB = bn + 8 * a + srow;
    gload_lds16(Bt + (size_t)rowB * K + schunk * 8, Bsw[0] + a * 512);
  }

  for (int it = 0; it < iters; ++it) {
    __syncthreads();
    const int cur = it & 1;
    if (it + 1 < iters) {
      const int k0 = 64 * (it + 1);
      #pragma unroll
      for (int t = 0; t < 4; ++t) {
        const int a = wave * 4 + t;
        const int rowA = min(bm + 8 * a + srow, M - 1);
        gload_lds16(A + (size_t)rowA * K + k0 + schunk * 8, Asw[cur ^ 1] + a * 512);
        const int rowB = bn + 8 * a + srow;
        gload_lds16(Bt + (size_t)rowB * K + k0 + schunk * 8, Bsw[cur ^ 1] + a * 512);
      }
    }
    #pragma unroll
    for (int kc = 0; kc < 2; ++kc) {
      short8 af[4], bfr[4];
      const int cq = 4 * kc + q;
      #pragma unroll
      for (int i = 0; i < 4; ++i) {
        const int ra = wm + 16 * i + l;
        af[i] = *(const short8*)&Asw[cur][ra * 64 + ((cq ^ (ra & 7)) * 8)];
        const int rb = wn + 16 * i + l;
        bfr[i] = *(const short8*)&Bsw[cur][rb * 64 + ((cq ^ (rb & 7)) * 8)];
      }
      #pragma unroll
      for (int i = 0; i < 4; ++i)
        #pragma unroll
        for (int j = 0; j < 4; ++j)
          acc[i][j] = __builtin_amdgcn_mfma_f32_16x16x32_bf16(af[i], bfr[j], acc[i][j], 0, 0, 0);
    }
  }

  float bv[4];
  #pragma unroll
  for (int j = 0; j < 4; ++j) bv[j] = bias[bn + wn + 16 * j + l];
  #pragma unroll
  for (int i = 0; i < 4; ++i) {
    #pragma unroll
    for (int r = 0; r < 4; ++r) {
      const int row = bm + wm + 16 * i + 4 * q + r;
      if (row >= M) continue;
      #pragma unroll
      for (int j = 0; j < 4; ++j)
        Cout[(size_t)row * Nn + bn + wn + 16 * j + l] = acc[i][j][r] + bv[j];
    }
  }
}

// ---------------- depthwise conv3d k3 s2 p1 + bias + LayerNorm -> bf16 ----------------
// one WAVE per output row, 8 channels/lane, vectorized, in-wave LN reduce.
__global__ __launch_bounds__(512) void conv_ln_kernel(
    const ushort* __restrict__ xb, const float* __restrict__ sr_wt,
    const float* __restrict__ sr_b, const float* __restrict__ sr_g,
    const float* __restrict__ sr_beta, ushort* __restrict__ xr_ln) {
  const int blk = xcd_swz(blockIdx.x, (B_ * NSR) / 8);
  const int wave = threadIdx.x >> 6, lane = threadIdx.x & 63;
  const int row = blk * 8 + wave;                  // 0..1999
  const int b = row / NSR, m = row % NSR;
  const int dr = m / 100, hr = (m / 10) % 10, wr = m % 10;
  const int c0 = lane * 8;

  float acc[8];
  #pragma unroll
  for (int e = 0; e < 8; ++e) acc[e] = 0.f;

  #pragma unroll
  for (int kd = 0; kd < 3; ++kd) {
    int din = 2 * dr + kd - 1;
    if (din < 0 || din >= DD) continue;
    #pragma unroll
    for (int kh = 0; kh < 3; ++kh) {
      int hin = 2 * hr + kh - 1;
      if (hin < 0 || hin >= DD) continue;
      #pragma unroll
      for (int kw = 0; kw < 3; ++kw) {
        int win = 2 * wr + kw - 1;
        if (win < 0 || win >= DD) continue;
        int nin = (din * DD + hin) * DD + win;
        short8 xv = *(const short8*)&xb[((size_t)b * N_ + nin) * C_ + c0];
        const float* wp = sr_wt + (kd * 9 + kh * 3 + kw) * C_ + c0;
        float4 w0 = *(const float4*)wp, w1 = *(const float4*)(wp + 4);
        acc[0] = fmaf(bf2f((ushort)xv[0]), w0.x, acc[0]);
        acc[1] = fmaf(bf2f((ushort)xv[1]), w0.y, acc[1]);
        acc[2] = fmaf(bf2f((ushort)xv[2]), w0.z, acc[2]);
        acc[3] = fmaf(bf2f((ushort)xv[3]), w0.w, acc[3]);
        acc[4] = fmaf(bf2f((ushort)xv[4]), w1.x, acc[4]);
        acc[5] = fmaf(bf2f((ushort)xv[5]), w1.y, acc[5]);
        acc[6] = fmaf(bf2f((ushort)xv[6]), w1.z, acc[6]);
        acc[7] = fmaf(bf2f((ushort)xv[7]), w1.w, acc[7]);
      }
    }
  }
  {
    float4 b0 = *(const float4*)&sr_b[c0], b1 = *(const float4*)&sr_b[c0 + 4];
    acc[0] += b0.x; acc[1] += b0.y; acc[2] += b0.z; acc[3] += b0.w;
    acc[4] += b1.x; acc[5] += b1.y; acc[6] += b1.z; acc[7] += b1.w;
  }
  float s1 = 0.f, s2 = 0.f;
  #pragma unroll
  for (int e = 0; e < 8; ++e) { s1 += acc[e]; s2 += acc[e] * acc[e]; }
  #pragma unroll
  for (int off = 32; off > 0; off >>= 1) {
    s1 += __shfl_xor(s1, off, 64);
    s2 += __shfl_xor(s2, off, 64);
  }
  const float mean = s1 * (1.f / C_);
  const float var = s2 * (1.f / C_) - mean * mean;
  const float r = rsqrtf(var + EPSF);
  float4 g0 = *(const float4*)&sr_g[c0], g1 = *(const float4*)&sr_g[c0 + 4];
  float4 e0 = *(const float4*)&sr_beta[c0], e1 = *(const float4*)&sr_beta[c0 + 4];
  const float gg[8] = {g0.x, g0.y, g0.z, g0.w, g1.x, g1.y, g1.z, g1.w};
  const float ee[8] = {e0.x, e0.y, e0.z, e0.w, e1.x, e1.y, e1.z, e1.w};
  ushort outv[8];
  #pragma unroll
  for (int e = 0; e < 8; ++e)
    outv[e] = f2bf((acc[e] - mean) * r * gg[e] + ee[e]);
  *(uint4*)&xr_ln[(size_t)row * C_ + c0] = *(uint4*)outv;
}

// ---------------- reformat KV bf16 into attention-ready swizzled slabs ----------------
__global__ __launch_bounds__(256) void reformat_kv(
    const ushort* __restrict__ KVh, ushort* __restrict__ Kg, ushort* __restrict__ Vg) {
  const int bh = blockIdx.x;            // b*8+h
  const int b = bh >> 3, h = bh & 7;
  const int tile = blockIdx.y;
  const int t0 = tile * 64;
  const size_t slab = ((size_t)bh * 16 + tile) * 4096;
  const int tid = threadIdx.x;
  #pragma unroll
  for (int i = 0; i < 2; ++i) {
    int w = tid + 256 * i;
    int key = w >> 3, ch = w & 7;
    int row = min(t0 + key, NSR - 1);
    uint4 v = *(const uint4*)&KVh[((size_t)b * NSR + row) * C2 + h * 64 + ch * 8];
    *(uint4*)&Kg[slab + key * 64 + ((ch ^ (key & 7)) * 8)] = v;
  }
  #pragma unroll
  for (int i = 0; i < 2; ++i) {
    int d = tid & 63, kc = (tid >> 6) + 4 * i;
    ushort u[8];
    #pragma unroll
    for (int e = 0; e < 8; ++e) {
      int row = min(t0 + kc * 8 + e, NSR - 1);
      u[e] = KVh[((size_t)b * NSR + row) * C2 + 512 + h * 64 + d];
    }
    *(uint4*)&Vg[slab + d * 64 + ((kc ^ (d & 7)) * 8)] = *(uint4*)u;
  }
}

// ---------------- MFMA flash attention (round-3/8 structure: 51.3us, proven optimum) ----------------
// grid = (32, 16), block 512 = 8 waves, 32 queries/wave (2 subtiles of 16).
// All 8 waves share one 16 KB K/V staging per tile -> 2 gload/wave.
// Blocks sharing a K/V slab (same bh) are XCD-contiguous via xcd_swz.
__global__ __launch_bounds__(512, 4) void attn_mfma_kernel(
    const ushort* __restrict__ Qb, const ushort* __restrict__ Kg,
    const ushort* __restrict__ Vg, ushort* __restrict__ Ob) {
  __shared__ __align__(16) ushort Kb[64 * 64];
  __shared__ __align__(16) ushort Vt[64 * 64];
  __shared__ __align__(16) ushort Pl[8][2][16 * 72];

  const int tid = threadIdx.x;
  const int wg = xcd_swz(blockIdx.y * 32 + blockIdx.x, 512);
  const int bh = wg >> 5;                        // 16 K/V-slab groups of 32 blocks
  const int b = bh >> 3, h = bh & 7;
  const int wave = tid >> 6, lane = tid & 63;
  const int l = lane & 15, q = lane >> 4;
  const int qw = (wg & 31) * 256 + wave * 32;    // 32*256 = 8192 (tail clamped)

  short8 qf[2][2];
  #pragma unroll
  for (int s = 0; s < 2; ++s) {
    const int row = min(qw + s * 16 + l, N_ - 1);
    const ushort* qp = Qb + ((size_t)b * N_ + row) * C_ + h * HD + q * 8;
    qf[s][0] = *(const short8*)(qp);
    qf[s][1] = *(const short8*)(qp + 32);
  }

  f32x4 o[2][4];
  #pragma unroll
  for (int s = 0; s < 2; ++s)
    #pragma unroll
    for (int td = 0; td < 4; ++td) o[s][td] = (f32x4){0.f, 0.f, 0.f, 0.f};
  float lrun[2] = {0.f, 0.f};

  const ushort* Kslab = Kg + (size_t)bh * 16 * 4096;
  const ushort* Vslab = Vg + (size_t)bh * 16 * 4096;

  for (int tile = 0; tile < 16; ++tile) {
    __syncthreads();
    // 8 waves x 1KB each covers the 8KB K and 8KB V tiles
    gload_lds16(Kslab + tile * 4096 + wave * 512 + lane * 8, Kb + wave * 512);
    gload_lds16(Vslab + tile * 4096 + wave * 512 + lane * 8, Vt + wave * 512);
    __syncthreads();

    // ---- hoist K fragments (read once, use for both subtiles) ----
    short8 af[2][4];
    #pragma unroll
    for (int kc = 0; kc < 2; ++kc) {
      const int cq = 4 * kc + q;
      #pragma unroll
      for (int t = 0; t < 4; ++t) {
        const int row = 16 * t + l;
        af[kc][t] = *(const short8*)&Kb[row * 64 + ((cq ^ (row & 7)) * 8)];
      }
    }
    // ---- QK + softmax per subtile ----
    #pragma unroll
    for (int s = 0; s < 2; ++s) {
      f32x4 sv[4];
      #pragma unroll
      for (int t = 0; t < 4; ++t) sv[t] = (f32x4){0.f, 0.f, 0.f, 0.f};
      #pragma unroll
      for (int kc = 0; kc < 2; ++kc)
        #pragma unroll
        for (int t = 0; t < 4; ++t)
          sv[t] = __builtin_amdgcn_mfma_f32_16x16x32_bf16(af[kc][t], qf[s][kc], sv[t], 0, 0, 0);
      if (tile == 15) {
        #pragma unroll
        for (int t = 0; t < 4; ++t)
          #pragma unroll
          for (int r = 0; r < 4; ++r)
            if (960 + 16 * t + 4 * q + r >= NSR) sv[t][r] = -1e30f;
      }
      float ssum = 0.f;
      #pragma unroll
      for (int t = 0; t < 4; ++t)
        #pragma unroll
        for (int r = 0; r < 4; ++r) {
          float p = __builtin_amdgcn_exp2f(sv[t][r]);
          sv[t][r] = p;
          ssum += p;
        }
      ssum += __shfl_xor(ssum, 16, 64);
      ssum += __shfl_xor(ssum, 32, 64);
      lrun[s] += ssum;
      #pragma unroll
      for (int t = 0; t < 4; ++t) {
        uint w0 = pkbf(sv[t][0], sv[t][1]);
        uint w1 = pkbf(sv[t][2], sv[t][3]);
        *(uint2*)&Pl[wave][s][l * 72 + 16 * t + 4 * q] = make_uint2(w0, w1);
      }
    }
    // ---- hoist V fragments, then PV for both subtiles ----
    short8 vf[2][4];
    #pragma unroll
    for (int kc = 0; kc < 2; ++kc) {
      const int cq = 4 * kc + q;
      #pragma unroll
      for (int td = 0; td < 4; ++td) {
        const int row = 16 * td + l;
        vf[kc][td] = *(const short8*)&Vt[row * 64 + ((cq ^ (row & 7)) * 8)];
      }
    }
    #pragma unroll
    for (int s = 0; s < 2; ++s)
      #pragma unroll
      for (int kc = 0; kc < 2; ++kc) {
        short8 pf = *(const short8*)&Pl[wave][s][l * 72 + 8 * q + 32 * kc];
        #pragma unroll
        for (int td = 0; td < 4; ++td)
          o[s][td] = __builtin_amdgcn_mfma_f32_16x16x32_bf16(pf, vf[kc][td], o[s][td], 0, 0, 0);
      }
  }

  // ---- epilogue ----
  #pragma unroll
  for (int s = 0; s < 2; ++s) {
    float linv[4];
    #pragma unroll
    for (int r = 0; r < 4; ++r) {
      float lv = __shfl(lrun[s], 4 * q + r, 16);
      linv[r] = 1.0f / lv;
    }
    #pragma unroll
    for (int td = 0; td < 4; ++td)
      #pragma unroll
      for (int r = 0; r < 4; ++r) {
        const int query = qw + s * 16 + 4 * q + r;
        if (query < N_)
          Ob[((size_t)b * N_ + query) * C_ + h * HD + 16 * td + l] =
              f2bf(o[s][td][r] * linv[r]);
      }
  }
}

// ---------------- trilinear upsample identity + LN + add -> bf16 out-proj input ----------------
// one WAVE per output row, 8 channels/lane, short8 loads, in-wave LN reduce.
__global__ __launch_bounds__(512) void ident_ln_add_kernel(
    const ushort* __restrict__ KVh, const float* __restrict__ up_g,
    const float* __restrict__ up_beta, const ushort* __restrict__ Ob,
    ushort* __restrict__ Obb) {
  const int blk = xcd_swz(blockIdx.x, (B_ * N_) / 8);
  const int wave = threadIdx.x >> 6, lane = threadIdx.x & 63;
  const int row = blk * 8 + wave;                // 0..15999
  const int b = row / N_, n = row % N_;
  const int od = n / 400, oh = (n / 20) % 20, ow = n % 20;
  int i0[3], i1[3]; float w0[3], w1[3];
  int oo[3] = {od, oh, ow};
  #pragma unroll
  for (int a = 0; a < 3; ++a) {
    int t = oo[a] >> 1;
    if (oo[a] & 1) { i0[a] = t; i1[a] = (t + 1 < DR) ? t + 1 : DR - 1; w0[a] = 0.75f; w1[a] = 0.25f; }
    else           { i0[a] = (t - 1 >= 0) ? t - 1 : 0; i1[a] = t;      w0[a] = 0.25f; w1[a] = 0.75f; }
  }
  const int c0 = lane * 8;
  float val[8];
  #pragma unroll
  for (int e = 0; e < 8; ++e) val[e] = 0.f;
  #pragma unroll
  for (int jd = 0; jd < 2; ++jd) {
    int id = jd ? i1[0] : i0[0]; float wd = jd ? w1[0] : w0[0];
    #pragma unroll
    for (int jh = 0; jh < 2; ++jh) {
      int ih = jh ? i1[1] : i0[1]; float wh = jh ? w1[1] : w0[1];
      #pragma unroll
      for (int jw = 0; jw < 2; ++jw) {
        int iw = jw ? i1[2] : i0[2]; float ww = jw ? w1[2] : w0[2];
        int mm = (id * DR + ih) * DR + iw;
        float wt = wd * wh * ww;
        short8 v = *(const short8*)&KVh[((size_t)b * NSR + mm) * C2 + C_ + c0];
        #pragma unroll
        for (int e = 0; e < 8; ++e)
          val[e] = fmaf(wt, bf2f((ushort)v[e]), val[e]);
      }
    }
  }
  float s1 = 0.f, s2 = 0.f;
  #pragma unroll
  for (int e = 0; e < 8; ++e) { s1 += val[e]; s2 += val[e] * val[e]; }
  #pragma unroll
  for (int off = 32; off > 0; off >>= 1) {
    s1 += __shfl_xor(s1, off, 64);
    s2 += __shfl_xor(s2, off, 64);
  }
  const float mean = s1 * (1.f / C_);
  const float var = s2 * (1.f / C_) - mean * mean;
  const float r = rsqrtf(var + EPSF);
  float4 g0 = *(const float4*)&up_g[c0], g1 = *(const float4*)&up_g[c0 + 4];
  float4 e0 = *(const float4*)&up_beta[c0], e1 = *(const float4*)&up_beta[c0 + 4];
  const float gg[8] = {g0.x, g0.y, g0.z, g0.w, g1.x, g1.y, g1.z, g1.w};
  const float ee[8] = {e0.x, e0.y, e0.z, e0.w, e1.x, e1.y, e1.z, e1.w};
  short8 ov = *(const short8*)&Ob[(size_t)row * C_ + c0];
  ushort outv[8];
  #pragma unroll
  for (int e = 0; e < 8; ++e)
    outv[e] = f2bf(bf2f((ushort)ov[e]) + (val[e] - mean) * r * gg[e] + ee[e]);
  *(uint4*)&Obb[(size_t)row * C_ + c0] = *(uint4*)outv;
}

extern "C" void kernel_launch(void* const* d_in, const int* in_sizes, int n_in,
                              void* d_out, int out_size, void* d_ws, size_t ws_size,
                              hipStream_t stream) {
  (void)in_sizes; (void)n_in; (void)out_size; (void)ws_size;
  const float* x       = (const float*)d_in[0];
  const float* Wq      = (const float*)d_in[1];
  const float* bq      = (const float*)d_in[2];
  const float* Wkv     = (const float*)d_in[3];
  const float* bkv     = (const float*)d_in[4];
  const float* sr_w    = (const float*)d_in[5];
  const float* sr_b    = (const float*)d_in[6];
  const float* sr_g    = (const float*)d_in[7];
  const float* sr_beta = (const float*)d_in[8];
  const float* up_g    = (const float*)d_in[9];
  const float* up_beta = (const float*)d_in[10];
  const float* Wp      = (const float*)d_in[11];
  const float* bp      = (const float*)d_in[12];
  float* out = (float*)d_out;

  // workspace (ushort units, ~61.3 MB + 55 KB)
  ushort* xb   = (ushort*)d_ws;                 // 8,192,000 (aliased by Obb after q-proj/conv)
  ushort* Qb   = xb + 8192000;                  // 8,192,000
  ushort* Ob   = Qb + 8192000;                  // 8,192,000
  ushort* XRb  = Ob + 8192000;                  // 1,024,000
  ushort* KVh  = XRb + 1024000;                 // 2,048,000
  ushort* Kg   = KVh + 2048000;                 // 1,048,576
  ushort* Vg   = Kg + 1048576;                  // 1,048,576
  ushort* Wqt  = Vg + 1048576;                  //   262,144
  ushort* Wkvt = Wqt + 262144;                  //   524,288
  ushort* Wpt  = Wkvt + 524288;                 //   262,144
  float*  sr_wt = (float*)(Wpt + 262144);       //    13,824 f
  ushort* Obb  = xb;

  // 0) fused prep: weights + sr_w + x->bf16
  prep_all<<<dim3(5025), 256, 0, stream>>>(Wq, Wkv, Wp, sr_w, x, Wqt, Wkvt, Wpt, sr_wt, xb);
  // 1) XRb = bf16(LN(conv3d_dw(x) + sr_b))   [wave-per-row, vectorized]
  conv_ln_kernel<<<dim3(B_ * NSR / 8), 512, 0, stream>>>(xb, sr_wt, sr_b, sr_g, sr_beta, XRb);
  // 2) fused dual GEMM: Qb = bf16((x@Wq+bq)*qscale)  ||  KVh = bf16(XRb@Wkv+bkv)
  gemm_dual<<<dim3(628), 256, 0, stream>>>(xb, Wqt, bq, Qb, XRb, Wkvt, bkv, KVh);
  // 3) Kg/Vg = attention-ready swizzled slabs
  reformat_kv<<<dim3(16, 16), 256, 0, stream>>>(KVh, Kg, Vg);
  // 4) Ob = bf16(softmax(QK^T) V)   [round-3/8 structure]
  attn_mfma_kernel<<<dim3(32, 16), 512, 0, stream>>>(Qb, Kg, Vg, Ob);
  // 5) Obb = bf16(Ob + LN(upsample(v)))   [wave-per-row, vectorized]
  ident_ln_add_kernel<<<dim3(B_ * N_ / 8), 512, 0, stream>>>(KVh, up_g, up_beta, Ob, Obb);
  // 6) out = Obb @ Wp + bp (fp32)
  gemm_mfma_f32<<<dim3(4, 125), 256, 0, stream>>>(Obb, Wpt, bp, out, B_ * N_, C_, C_);
}